// Round 1
// baseline (911.774 us; speedup 1.0000x reference)
//
#include <hip/hip_runtime.h>
#include <cstddef>

#define NN 50000
#define NP 50048      // padded rows (391 * 128)
#define RT 391        // row tiles

typedef unsigned short u16;
typedef __attribute__((ext_vector_type(8))) short bf16x8;
typedef __attribute__((ext_vector_type(4))) float f32x4;

__device__ __forceinline__ float bf2f(u16 h){
  union { unsigned u; float f; } x; x.u = ((unsigned)h) << 16; return x.f;
}
__device__ __forceinline__ u16 f2bf(float f){
  union { float f; unsigned u; } x; x.f = f;
  unsigned r = x.u + 0x7fffu + ((x.u >> 16) & 1u);
  return (u16)(r >> 16);
}
__device__ __forceinline__ float silu_f(float v){
  return v / (1.f + __expf(-v));
}
__device__ __forceinline__ void gll16(const u16* g, u16* l){
  __builtin_amdgcn_global_load_lds(
      (const __attribute__((address_space(1))) unsigned int*)g,
      (__attribute__((address_space(3))) unsigned int*)l, 16, 0, 0);
}

// ---------------- weight convert + transpose to bf16 ----------------
// big (6): [512,512] -> Wt[c][k] at WT + m*262144
// small(6): [256,128] -> Wt[c][k] at WT + 6*262144 + m*32768
__global__ __launch_bounds__(256)
void k_wconv(const float* b0,const float* b1,const float* b2,const float* b3,
             const float* b4,const float* b5,
             const float* s0,const float* s1,const float* s2,const float* s3,
             const float* s4,const float* s5, u16* __restrict__ dst){
  int idx = blockIdx.x * 256 + threadIdx.x;
  if(idx < 6*262144){
    int m = idx >> 18; int r = idx & 262143; int c = r >> 9; int k = r & 511;
    const float* src = m==0?b0:m==1?b1:m==2?b2:m==3?b3:m==4?b4:b5;
    dst[idx] = f2bf(src[k*512 + c]);
  } else {
    int j = idx - 6*262144;
    int m = j >> 15; int r = j & 32767; int c = r >> 8; int k = r & 255;
    const float* src = m==0?s0:m==1?s1:m==2?s2:m==3?s3:m==4?s4:s5;
    dst[idx] = f2bf(src[k*128 + c]);
  }
}

// ---------------- prep: A0 = bf16[ s | ||v|| ]  [NP,512] ----------------
__global__ __launch_bounds__(256)
void k_prep(const float* __restrict__ x, u16* __restrict__ A0){
  const int n = blockIdx.x;
  const int t = threadIdx.x;          // 0..255
  u16* row = A0 + (size_t)n * 512;
  if(n >= NN){ row[t] = 0; row[256 + t] = 0; return; }
  const float* xr = x + (size_t)n * 1024;
  row[t] = f2bf(xr[t]);
  float a = xr[256 + 3*t], b = xr[256 + 3*t + 1], c = xr[256 + 3*t + 2];
  row[256 + t] = f2bf(sqrtf(a*a + b*b + c*c));
}

// ---------------- shared 128x128 MFMA tile core (BK=32) ----------------
template<int K>
__device__ __forceinline__ void gemm_tile(const u16* __restrict__ A, int lda,
                                          const u16* __restrict__ Bt, int ldb,
                                          u16* lA, u16* lB, f32x4 acc[4][4]){
  const int tid  = threadIdx.x;
  const int lane = tid & 63;
  const int wid  = tid >> 6;
  const int wm = (wid >> 1) << 6;
  const int wn = (wid & 1) << 6;
  const int lr = lane & 15;
  const int lh = lane >> 4;
#pragma unroll
  for(int mi=0;mi<4;mi++)
#pragma unroll
    for(int ni=0;ni<4;ni++) acc[mi][ni] = (f32x4)(0.f);
  const int e1 = tid + 256;
  const u16* ag0 = A  + (size_t)(tid>>2)*lda + (tid&3)*8;
  const u16* ag1 = A  + (size_t)(e1 >>2)*lda + (e1 &3)*8;
  const u16* bg0 = Bt + (size_t)(tid>>2)*ldb + (tid&3)*8;
  const u16* bg1 = Bt + (size_t)(e1 >>2)*ldb + (e1 &3)*8;
  u16* la0 = lA + tid*8; u16* la1 = lA + e1*8;
  u16* lb0 = lB + tid*8; u16* lb1 = lB + e1*8;
  for(int k0=0;k0<K;k0+=32){
    gll16(ag0 + k0, la0);
    gll16(ag1 + k0, la1);
    gll16(bg0 + k0, lb0);
    gll16(bg1 + k0, lb1);
    __syncthreads();
    bf16x8 af[4], bfv[4];
#pragma unroll
    for(int i=0;i<4;i++){
      af[i]  = *(const bf16x8*)(lA + ((wm + i*16 + lr)<<5) + (lh<<3));
      bfv[i] = *(const bf16x8*)(lB + ((wn + i*16 + lr)<<5) + (lh<<3));
    }
#pragma unroll
    for(int mi=0;mi<4;mi++)
#pragma unroll
      for(int ni=0;ni<4;ni++)
        acc[mi][ni] = __builtin_amdgcn_mfma_f32_16x16x32_bf16(
                          af[mi], bfv[ni], acc[mi][ni], 0, 0, 0);
    __syncthreads();
  }
}

// ---------------- fc GEMMs: [NP,512]@[512,512], z selects branch -------
// EPI 0: out = silu(acc+bias) -> bf16 [n*512+c]
// EPI 1: gate vs x:   c<256 -> silu; c>=256 -> v(x) * g  -> [n*1024+...]
// EPI 2: gate vs TPV: c<256 -> silu; c>=256 -> tpv * g
template<int EPI>
__global__ __launch_bounds__(256)
void k_fc(const u16* __restrict__ Al, const u16* __restrict__ Ar,
          const u16* __restrict__ Btl, const u16* __restrict__ Btr,
          const float* __restrict__ bl, const float* __restrict__ br_,
          u16* __restrict__ ol, u16* __restrict__ orr,
          const float* __restrict__ xg, const u16* __restrict__ tpv){
  __shared__ u16 lA[4096];
  __shared__ u16 lB[4096];
  const int z = blockIdx.z;
  const u16* A  = z ? Ar  : Al;
  const u16* Bt = z ? Btr : Btl;
  const float* bias = z ? br_ : bl;
  u16* o = z ? orr : ol;
  const int tileRow = blockIdx.x << 7;
  const int colTile = blockIdx.y << 7;
  f32x4 acc[4][4];
  gemm_tile<512>(A + (size_t)tileRow*512, 512, Bt + (size_t)colTile*512, 512,
                 lA, lB, acc);
  const int tid = threadIdx.x, lane = tid & 63, wid = tid >> 6;
  const int wm=(wid>>1)<<6, wn=(wid&1)<<6, lr=lane&15, lh=lane>>4;
#pragma unroll
  for(int mi=0;mi<4;mi++){
#pragma unroll
    for(int ni=0;ni<4;ni++){
      const int c = colTile + wn + ni*16 + lr;
      const float bv = bias[c];
#pragma unroll
      for(int r=0;r<4;r++){
        const int n = tileRow + wm + mi*16 + lh*4 + r;
        float v = acc[mi][ni][r] + bv;
        if(EPI == 0){
          o[(size_t)n*512 + c] = f2bf(silu_f(v));
        } else {
          if(c < 256){
            o[(size_t)n*1024 + c] = f2bf(silu_f(v));
          } else {
            const int u = c - 256;
            float v0, v1, v2;
            if(EPI == 1){
              if(n < NN){
                const float* xv = xg + (size_t)n*1024 + 256 + 3*u;
                v0 = xv[0]; v1 = xv[1]; v2 = xv[2];
              } else { v0 = 0.f; v1 = 0.f; v2 = 0.f; }
            } else {
              const u16* tv = tpv + (size_t)n*768 + u;
              v0 = bf2f(tv[0]); v1 = bf2f(tv[256]); v2 = bf2f(tv[512]);
            }
            u16* ob = o + (size_t)n*1024 + 256 + u;
            ob[0]   = f2bf(v0 * v);
            ob[256] = f2bf(v1 * v);
            ob[512] = f2bf(v2 * v);
          }
        }
      }
    }
  }
}

// ---------------- o3 GEMMs: [NP,256]@[256,128] ----------------
// EPI 0: branch o3 -> bf16 [n*512 + (comp? 128+(comp-1)*128+c : c)], z=b*4+comp
// EPI 1: final  -> fp32 d_out, z=comp (0:s, 1..3: vector comp)
template<int EPI>
__global__ __launch_bounds__(256)
void k_o3(const u16* __restrict__ AL, const u16* __restrict__ AR,
          const u16* __restrict__ W0L, const u16* __restrict__ W1L,
          const u16* __restrict__ W0R, const u16* __restrict__ W1R,
          const float* __restrict__ bL, const float* __restrict__ bR,
          u16* __restrict__ oL, u16* __restrict__ oR,
          float* __restrict__ fout){
  __shared__ u16 lA[4096];
  __shared__ u16 lB[4096];
  const int z = blockIdx.z;
  const int br   = (EPI==0) ? (z >> 2) : 0;
  const int comp = (EPI==0) ? (z & 3)  : z;
  const u16* A  = br ? AR : AL;
  const u16* Bt = br ? (comp ? W1R : W0R) : (comp ? W1L : W0L);
  const float* bias = br ? bR : bL;
  u16* o16 = br ? oR : oL;
  const int aoff = comp ? (256 + (comp-1)*256) : 0;
  const int tileRow = blockIdx.x << 7;
  f32x4 acc[4][4];
  gemm_tile<256>(A + (size_t)tileRow*1024 + aoff, 1024, Bt, 256, lA, lB, acc);
  const int tid = threadIdx.x, lane = tid & 63, wid = tid >> 6;
  const int wm=(wid>>1)<<6, wn=(wid&1)<<6, lr=lane&15, lh=lane>>4;
#pragma unroll
  for(int mi=0;mi<4;mi++){
#pragma unroll
    for(int ni=0;ni<4;ni++){
      const int c = wn + ni*16 + lr;    // 0..127
#pragma unroll
      for(int r=0;r<4;r++){
        const int n = tileRow + wm + mi*16 + lh*4 + r;
        float v = acc[mi][ni][r] * 0.0625f;   // 1/sqrt(256)
        if(EPI == 0){
          if(comp == 0) v += bias[c];
          const int cc = (comp == 0) ? c : (128 + (comp-1)*128 + c);
          o16[(size_t)n*512 + cc] = f2bf(v);
        } else {
          if(n < NN){
            if(comp == 0) fout[(size_t)n*512 + c] = v + bias[c];
            else          fout[(size_t)n*512 + 128 + c*3 + (comp-1)] = v;
          }
        }
      }
    }
  }
}

// ------------- TP + residual + norms: builds A2 [NP,512], TPV [NP,3,256] ---
__global__ __launch_bounds__(256)
void k_tp(const u16* __restrict__ OL, const u16* __restrict__ ORr,
          const float* __restrict__ x,
          const float* __restrict__ w_ss, const float* __restrict__ w_sv,
          const float* __restrict__ w_vs, const float* __restrict__ w_vv,
          u16* __restrict__ A2, u16* __restrict__ TPV){
  const int n = (blockIdx.x << 1) + (threadIdx.x >> 7);
  const int h = threadIdx.x & 127;
  const u16* ol  = OL  + (size_t)n * 512;
  const u16* orv = ORr + (size_t)n * 512;
  const float ls = bf2f(ol[h]),  rs = bf2f(orv[h]);
  const float lv0=bf2f(ol[128+h]),  lv1=bf2f(ol[256+h]),  lv2=bf2f(ol[384+h]);
  const float rv0=bf2f(orv[128+h]), rv1=bf2f(orv[256+h]), rv2=bf2f(orv[384+h]);
  const float wss=w_ss[h], wsv=w_sv[h], wvs=w_vs[h], wvv=w_vv[h];
  float sa = wss * ls * rs;
  float sb = wvv * (lv0*rv0 + lv1*rv1 + lv2*rv2) * 0.5773502691896258f;
  float va0 = wsv*ls*rv0, va1 = wsv*ls*rv1, va2 = wsv*ls*rv2;
  float vb0 = wvs*lv0*rs, vb1 = wvs*lv1*rs, vb2 = wvs*lv2*rs;
  if(n < NN){
    const float* xr = x + (size_t)n * 1024;
    sa += xr[h]; sb += xr[128 + h];
    va0 += xr[256 + 3*h];     va1 += xr[256 + 3*h + 1];   va2 += xr[256 + 3*h + 2];
    const int h2 = 128 + h;
    vb0 += xr[256 + 3*h2];    vb1 += xr[256 + 3*h2 + 1];  vb2 += xr[256 + 3*h2 + 2];
  }
  u16* a2 = A2 + (size_t)n * 512;
  a2[h]       = f2bf(sa);
  a2[128 + h] = f2bf(sb);
  a2[256 + h] = f2bf(sqrtf(va0*va0 + va1*va1 + va2*va2));
  a2[384 + h] = f2bf(sqrtf(vb0*vb0 + vb1*vb1 + vb2*vb2));
  u16* tv = TPV + (size_t)n * 768;
  tv[h]       = f2bf(va0);  tv[128 + h] = f2bf(vb0);
  tv[256 + h] = f2bf(va1);  tv[384 + h] = f2bf(vb1);
  tv[512 + h] = f2bf(va2);  tv[640 + h] = f2bf(vb2);
}

extern "C" void kernel_launch(void* const* d_in, const int* in_sizes, int n_in,
                              void* d_out, int out_size, void* d_ws, size_t ws_size,
                              hipStream_t stream){
  const float* x      = (const float*)d_in[0];
  const float* fcl1_w = (const float*)d_in[1];  const float* fcl1_b = (const float*)d_in[2];
  const float* fcl2_w = (const float*)d_in[3];  const float* fcl2_b = (const float*)d_in[4];
  const float* fcr1_w = (const float*)d_in[5];  const float* fcr1_b = (const float*)d_in[6];
  const float* fcr2_w = (const float*)d_in[7];  const float* fcr2_b = (const float*)d_in[8];
  const float* fcp1_w = (const float*)d_in[9];  const float* fcp1_b = (const float*)d_in[10];
  const float* fcp2_w = (const float*)d_in[11]; const float* fcp2_b = (const float*)d_in[12];
  const float* Wl0 = (const float*)d_in[13]; const float* bl0 = (const float*)d_in[14];
  const float* Wl1 = (const float*)d_in[15];
  const float* Wr0 = (const float*)d_in[16]; const float* br0 = (const float*)d_in[17];
  const float* Wr1 = (const float*)d_in[18];
  const float* Wp0 = (const float*)d_in[19]; const float* bp0 = (const float*)d_in[20];
  const float* Wp1 = (const float*)d_in[21];
  const float* w_ss = (const float*)d_in[22]; const float* w_sv = (const float*)d_in[23];
  const float* w_vs = (const float*)d_in[24]; const float* w_vv = (const float*)d_in[25];
  float* out = (float*)d_out;

  // ---- ws layout ----
  u16* WT = (u16*)d_ws;                         // bf16-transposed weights
  u16* wt_fcl1 = WT + 0*262144;
  u16* wt_fcl2 = WT + 1*262144;
  u16* wt_fcr1 = WT + 2*262144;
  u16* wt_fcr2 = WT + 3*262144;
  u16* wt_fcp1 = WT + 4*262144;
  u16* wt_fcp2 = WT + 5*262144;
  u16* wt_sm  = WT + 6*262144;
  u16* wt_Wl0 = wt_sm + 0*32768;
  u16* wt_Wl1 = wt_sm + 1*32768;
  u16* wt_Wr0 = wt_sm + 2*32768;
  u16* wt_Wr1 = wt_sm + 3*32768;
  u16* wt_Wp0 = wt_sm + 4*32768;
  u16* wt_Wp1 = wt_sm + 5*32768;
  char* base = (char*)d_ws;
  const size_t SZ512  = (size_t)NP * 512 * 2;   // 51.25 MB
  const size_t SZ1024 = (size_t)NP * 1024 * 2;  // 102.5 MB
  const size_t W_RES  = (size_t)4 << 20;        // 4 MB reserved for weights
  u16* A0 = (u16*)(base + W_RES);                       // A0, later A2
  u16* Hl = (u16*)(base + W_RES + 1*SZ512);             // H_l, OL, H_p
  u16* Hr = (u16*)(base + W_RES + 2*SZ512);             // H_r, OR
  u16* BL = (u16*)(base + W_RES + 3*SZ512);             // ls/lv left; later TPV
  u16* BR = (u16*)(base + W_RES + 3*SZ512 + SZ1024);    // ls/lv right; later PS/PV
  (void)ws_size; (void)in_sizes; (void)n_in; (void)out_size;

  // 1. weights -> bf16 transposed
  k_wconv<<<6912, 256, 0, stream>>>(fcl1_w, fcl2_w, fcr1_w, fcr2_w, fcp1_w, fcp2_w,
                                    Wl0, Wl1, Wr0, Wr1, Wp0, Wp1, WT);
  // 2. A0 = [s | ||v||] bf16
  k_prep<<<NP, 256, 0, stream>>>(x, A0);
  // 3. fc1 (L,R): H = silu(A0 @ W1 + b1)
  k_fc<0><<<dim3(RT,4,2), 256, 0, stream>>>(A0, A0, wt_fcl1, wt_fcr1,
                                            fcl1_b, fcr1_b, Hl, Hr, nullptr, nullptr);
  // 4. fc2 (L,R) + gate vs x -> BL/BR = [silu(g_s) | v*g_v]
  k_fc<1><<<dim3(RT,4,2), 256, 0, stream>>>(Hl, Hr, wt_fcl2, wt_fcr2,
                                            fcl2_b, fcr2_b, BL, BR, x, nullptr);
  // 5. o3 linears (2 branches x 4 comps) -> OL(Hl), OR(Hr)
  k_o3<0><<<dim3(RT,1,8), 256, 0, stream>>>(BL, BR, wt_Wl0, wt_Wl1, wt_Wr0, wt_Wr1,
                                            bl0, br0, Hl, Hr, nullptr);
  // 6. tensor product + residual + norms -> A2(A0), TPV(BL)
  k_tp<<<NP/2, 256, 0, stream>>>(Hl, Hr, x, w_ss, w_sv, w_vs, w_vv, A0, BL);
  // 7. fcp1: H_p = silu(A2 @ Wp1 + b) -> Hl
  k_fc<0><<<dim3(RT,4,1), 256, 0, stream>>>(A0, A0, wt_fcp1, wt_fcp1,
                                            fcp1_b, fcp1_b, Hl, Hl, nullptr, nullptr);
  // 8. fcp2 + gate vs TPV -> BR = [PS | PV]
  k_fc<2><<<dim3(RT,4,1), 256, 0, stream>>>(Hl, Hl, wt_fcp2, wt_fcp2,
                                            fcp2_b, fcp2_b, BR, BR, nullptr, BL);
  // 9. final o3 -> d_out fp32
  k_o3<1><<<dim3(RT,1,4), 256, 0, stream>>>(BR, BR, wt_Wp0, wt_Wp1, nullptr, nullptr,
                                            bp0, bp0, nullptr, nullptr, out);
}

// Round 2
// 860.633 us; speedup vs baseline: 1.0594x; 1.0594x over previous
//
#include <hip/hip_runtime.h>
#include <cstddef>

#define NN 50000
#define NP 50048      // padded rows (391 * 128)
#define RT 391        // row tiles

typedef unsigned short u16;
typedef __attribute__((ext_vector_type(8))) short bf16x8;
typedef __attribute__((ext_vector_type(4))) float f32x4;

__device__ __forceinline__ float bf2f(u16 h){
  union { unsigned u; float f; } x; x.u = ((unsigned)h) << 16; return x.f;
}
__device__ __forceinline__ u16 f2bf(float f){
  union { float f; unsigned u; } x; x.f = f;
  unsigned r = x.u + 0x7fffu + ((x.u >> 16) & 1u);
  return (u16)(r >> 16);
}
__device__ __forceinline__ float silu_f(float v){
  return v / (1.f + __expf(-v));
}
__device__ __forceinline__ void gll16(const u16* g, u16* l){
  __builtin_amdgcn_global_load_lds(
      (const __attribute__((address_space(1))) unsigned int*)g,
      (__attribute__((address_space(3))) unsigned int*)l, 16, 0, 0);
}
// bijective XCD-chunked block-id swizzle (m204)
__device__ __forceinline__ int xcd_swz(int hw, int nblk){
  int q = nblk >> 3, r = nblk & 7;
  int xcd = hw & 7, j = hw >> 3;
  return (xcd < r ? xcd*(q+1) : r*(q+1) + (xcd - r)*q) + j;
}
#define SWZ(row) (((row) >> 1) & 3)

// ---------------- weight convert + transpose to bf16 ----------------
__global__ __launch_bounds__(256)
void k_wconv(const float* b0,const float* b1,const float* b2,const float* b3,
             const float* b4,const float* b5,
             const float* s0,const float* s1,const float* s2,const float* s3,
             const float* s4,const float* s5, u16* __restrict__ dst){
  int idx = blockIdx.x * 256 + threadIdx.x;
  if(idx < 6*262144){
    int m = idx >> 18; int r = idx & 262143; int c = r >> 9; int k = r & 511;
    const float* src = m==0?b0:m==1?b1:m==2?b2:m==3?b3:m==4?b4:b5;
    dst[idx] = f2bf(src[k*512 + c]);
  } else {
    int j = idx - 6*262144;
    int m = j >> 15; int r = j & 32767; int c = r >> 8; int k = r & 255;
    const float* src = m==0?s0:m==1?s1:m==2?s2:m==3?s3:m==4?s4:s5;
    dst[idx] = f2bf(src[k*128 + c]);
  }
}

// ---------------- prep: A0 = bf16[ s | ||v|| ]  [NP,512] ----------------
__global__ __launch_bounds__(256)
void k_prep(const float* __restrict__ x, u16* __restrict__ A0){
  const int n = blockIdx.x;
  const int t = threadIdx.x;
  u16* row = A0 + (size_t)n * 512;
  if(n >= NN){ row[t] = 0; row[256 + t] = 0; return; }
  const float* xr = x + (size_t)n * 1024;
  row[t] = f2bf(xr[t]);
  float a = xr[256 + 3*t], b = xr[256 + 3*t + 1], c = xr[256 + 3*t + 2];
  row[256 + t] = f2bf(sqrtf(a*a + b*b + c*c));
}

// ------- 128x128 MFMA tile core: double-buffered, counted vmcnt, swizzled ----
// lds: 16384 u16 = 32 KB: [buf0: A 4096 | B 4096][buf1: A 4096 | B 4096]
template<int K>
__device__ __forceinline__ void gemm_core(const u16* __restrict__ A, int lda,
                                          const u16* __restrict__ Bt, int ldb,
                                          u16* lds, f32x4 acc[4][4]){
  const int tid  = threadIdx.x;
  const int lane = tid & 63;
  const int wid  = tid >> 6;
  const int wm = (wid >> 1) << 6;
  const int wn = (wid & 1) << 6;
  const int lr = lane & 15;
  const int lh = lane >> 4;
#pragma unroll
  for(int mi=0;mi<4;mi++)
#pragma unroll
    for(int ni=0;ni<4;ni++) acc[mi][ni] = (f32x4)(0.f);

  // staging addresses: entry e in [0,512): row=e>>2, slot=e&3; source k-chunk
  // is pre-swizzled (slot ^ SWZ(row)) so LDS dest stays linear (rule #21)
  const int r0 = tid >> 2,        s0 = tid & 3;
  const int r1 = (tid + 256) >> 2;              // slot same as s0
  const u16* agA0 = A  + (size_t)r0*lda + (size_t)((s0 ^ SWZ(r0)) * 8);
  const u16* agA1 = A  + (size_t)r1*lda + (size_t)((s0 ^ SWZ(r1)) * 8);
  const u16* agB0 = Bt + (size_t)r0*ldb + (size_t)((s0 ^ SWZ(r0)) * 8);
  const u16* agB1 = Bt + (size_t)r1*ldb + (size_t)((s0 ^ SWZ(r1)) * 8);

  constexpr int NT = K / 32;

#define STAGE(b, k0)                                         \
  { u16* lbase = lds + (b) * 8192;                           \
    gll16(agA0 + (k0), lbase + tid*8);                       \
    gll16(agA1 + (k0), lbase + (tid+256)*8);                 \
    gll16(agB0 + (k0), lbase + 4096 + tid*8);                \
    gll16(agB1 + (k0), lbase + 4096 + (tid+256)*8); }

  STAGE(0, 0)
  for(int kt = 0; kt < NT; ++kt){
    const int cur = kt & 1;
    const int knext = ((kt + 1) & (NT - 1)) * 32;   // wrap: keeps vmcnt uniform
    STAGE(cur ^ 1, knext)
    asm volatile("s_waitcnt vmcnt(4)" ::: "memory"); // cur's 4 done, next's stay in flight
    __builtin_amdgcn_s_barrier();
    asm volatile("" ::: "memory");
    const u16* la = lds + cur * 8192;
    const u16* lb = la + 4096;
    bf16x8 af[4], bv[4];
#pragma unroll
    for(int i=0;i<4;i++){
      const int ra = wm + i*16 + lr;
      af[i] = *(const bf16x8*)(la + ra*32 + ((lh ^ SWZ(ra)) * 8));
      const int rb = wn + i*16 + lr;
      bv[i] = *(const bf16x8*)(lb + rb*32 + ((lh ^ SWZ(rb)) * 8));
    }
#pragma unroll
    for(int mi=0;mi<4;mi++)
#pragma unroll
      for(int ni=0;ni<4;ni++)
        acc[mi][ni] = __builtin_amdgcn_mfma_f32_16x16x32_bf16(
                          af[mi], bv[ni], acc[mi][ni], 0, 0, 0);
    asm volatile("" ::: "memory");
    __builtin_amdgcn_s_barrier();
    asm volatile("" ::: "memory");
  }
#undef STAGE
}

// ---------------- fc GEMMs: [NP,512]@[512,512] ----------------
// EPI 0: out = silu(acc+bias) -> bf16 [n*512+c]
// EPI 1: gate vs x;  EPI 2: gate vs TPV
template<int EPI, int NZ>
__global__ __launch_bounds__(256)
void k_fc(const u16* __restrict__ Al, const u16* __restrict__ Ar,
          const u16* __restrict__ Btl, const u16* __restrict__ Btr,
          const float* __restrict__ bl, const float* __restrict__ br_,
          u16* __restrict__ ol, u16* __restrict__ orr,
          const float* __restrict__ xg, const u16* __restrict__ tpv){
  __shared__ u16 lds[16384];
  const int nblk = RT * 4 * NZ;
  const int L = xcd_swz(blockIdx.x, nblk);
  int rowTileI, colTileI, z;
  if(NZ == 2){ rowTileI = L >> 3; int sub = L & 7; colTileI = sub >> 1; z = sub & 1; }
  else       { rowTileI = L >> 2; colTileI = L & 3; z = 0; }
  const u16* A  = z ? Ar  : Al;
  const u16* Bt = z ? Btr : Btl;
  const float* bias = z ? br_ : bl;
  u16* o = z ? orr : ol;
  const int tileRow = rowTileI << 7;
  const int colTile = colTileI << 7;
  f32x4 acc[4][4];
  gemm_core<512>(A + (size_t)tileRow*512, 512, Bt + (size_t)colTile*512, 512,
                 lds, acc);
  const int tid = threadIdx.x, lane = tid & 63, wid = tid >> 6;
  const int wm=(wid>>1)<<6, wn=(wid&1)<<6, lr=lane&15, lh=lane>>4;
#pragma unroll
  for(int mi=0;mi<4;mi++){
#pragma unroll
    for(int ni=0;ni<4;ni++){
      const int c = colTile + wn + ni*16 + lr;
      const float bv = bias[c];
#pragma unroll
      for(int r=0;r<4;r++){
        const int n = tileRow + wm + mi*16 + lh*4 + r;
        float v = acc[mi][ni][r] + bv;
        if(EPI == 0){
          o[(size_t)n*512 + c] = f2bf(silu_f(v));
        } else {
          if(c < 256){
            o[(size_t)n*1024 + c] = f2bf(silu_f(v));
          } else {
            const int u = c - 256;
            float v0, v1, v2;
            if(EPI == 1){
              if(n < NN){
                const float* xv = xg + (size_t)n*1024 + 256 + 3*u;
                v0 = xv[0]; v1 = xv[1]; v2 = xv[2];
              } else { v0 = 0.f; v1 = 0.f; v2 = 0.f; }
            } else {
              const u16* tv = tpv + (size_t)n*768 + u;
              v0 = bf2f(tv[0]); v1 = bf2f(tv[256]); v2 = bf2f(tv[512]);
            }
            u16* ob = o + (size_t)n*1024 + 256 + u;
            ob[0]   = f2bf(v0 * v);
            ob[256] = f2bf(v1 * v);
            ob[512] = f2bf(v2 * v);
          }
        }
      }
    }
  }
}

// ---------------- o3 GEMMs: [NP,256]@[256,128] ----------------
template<int EPI>
__global__ __launch_bounds__(256)
void k_o3(const u16* __restrict__ AL, const u16* __restrict__ AR,
          const u16* __restrict__ W0L, const u16* __restrict__ W1L,
          const u16* __restrict__ W0R, const u16* __restrict__ W1R,
          const float* __restrict__ bL, const float* __restrict__ bR,
          u16* __restrict__ oL, u16* __restrict__ oR,
          float* __restrict__ fout){
  __shared__ u16 lds[16384];
  const int nblk = RT * ((EPI==0) ? 8 : 4);
  const int L = xcd_swz(blockIdx.x, nblk);
  int rowTileI, br, comp;
  if(EPI == 0){ rowTileI = L >> 3; int sub = L & 7; br = sub >> 2; comp = sub & 3; }
  else        { rowTileI = L >> 2; comp = L & 3; br = 0; }
  const u16* A  = br ? AR : AL;
  const u16* Bt = br ? (comp ? W1R : W0R) : (comp ? W1L : W0L);
  const float* bias = br ? bR : bL;
  u16* o16 = br ? oR : oL;
  const int aoff = comp ? (256 + (comp-1)*256) : 0;
  const int tileRow = rowTileI << 7;
  f32x4 acc[4][4];
  gemm_core<256>(A + (size_t)tileRow*1024 + aoff, 1024, Bt, 256, lds, acc);
  const int tid = threadIdx.x, lane = tid & 63, wid = tid >> 6;
  const int wm=(wid>>1)<<6, wn=(wid&1)<<6, lr=lane&15, lh=lane>>4;
#pragma unroll
  for(int mi=0;mi<4;mi++){
#pragma unroll
    for(int ni=0;ni<4;ni++){
      const int c = wn + ni*16 + lr;    // 0..127
#pragma unroll
      for(int r=0;r<4;r++){
        const int n = tileRow + wm + mi*16 + lh*4 + r;
        float v = acc[mi][ni][r] * 0.0625f;   // 1/sqrt(256)
        if(EPI == 0){
          if(comp == 0) v += bias[c];
          const int cc = (comp == 0) ? c : (128 + (comp-1)*128 + c);
          o16[(size_t)n*512 + cc] = f2bf(v);
        } else {
          if(n < NN){
            if(comp == 0) fout[(size_t)n*512 + c] = v + bias[c];
            else          fout[(size_t)n*512 + 128 + c*3 + (comp-1)] = v;
          }
        }
      }
    }
  }
}

// ------------- TP + residual + norms: builds A2 [NP,512], TPV [NP,3,256] ---
__global__ __launch_bounds__(256)
void k_tp(const u16* __restrict__ OL, const u16* __restrict__ ORr,
          const float* __restrict__ x,
          const float* __restrict__ w_ss, const float* __restrict__ w_sv,
          const float* __restrict__ w_vs, const float* __restrict__ w_vv,
          u16* __restrict__ A2, u16* __restrict__ TPV){
  const int n = (blockIdx.x << 1) + (threadIdx.x >> 7);
  const int h = threadIdx.x & 127;
  const u16* ol  = OL  + (size_t)n * 512;
  const u16* orv = ORr + (size_t)n * 512;
  const float ls = bf2f(ol[h]),  rs = bf2f(orv[h]);
  const float lv0=bf2f(ol[128+h]),  lv1=bf2f(ol[256+h]),  lv2=bf2f(ol[384+h]);
  const float rv0=bf2f(orv[128+h]), rv1=bf2f(orv[256+h]), rv2=bf2f(orv[384+h]);
  const float wss=w_ss[h], wsv=w_sv[h], wvs=w_vs[h], wvv=w_vv[h];
  float sa = wss * ls * rs;
  float sb = wvv * (lv0*rv0 + lv1*rv1 + lv2*rv2) * 0.5773502691896258f;
  float va0 = wsv*ls*rv0, va1 = wsv*ls*rv1, va2 = wsv*ls*rv2;
  float vb0 = wvs*lv0*rs, vb1 = wvs*lv1*rs, vb2 = wvs*lv2*rs;
  if(n < NN){
    const float* xr = x + (size_t)n * 1024;
    sa += xr[h]; sb += xr[128 + h];
    va0 += xr[256 + 3*h];     va1 += xr[256 + 3*h + 1];   va2 += xr[256 + 3*h + 2];
    const int h2 = 128 + h;
    vb0 += xr[256 + 3*h2];    vb1 += xr[256 + 3*h2 + 1];  vb2 += xr[256 + 3*h2 + 2];
  }
  u16* a2 = A2 + (size_t)n * 512;
  a2[h]       = f2bf(sa);
  a2[128 + h] = f2bf(sb);
  a2[256 + h] = f2bf(sqrtf(va0*va0 + va1*va1 + va2*va2));
  a2[384 + h] = f2bf(sqrtf(vb0*vb0 + vb1*vb1 + vb2*vb2));
  u16* tv = TPV + (size_t)n * 768;
  tv[h]       = f2bf(va0);  tv[128 + h] = f2bf(vb0);
  tv[256 + h] = f2bf(va1);  tv[384 + h] = f2bf(vb1);
  tv[512 + h] = f2bf(va2);  tv[640 + h] = f2bf(vb2);
}

extern "C" void kernel_launch(void* const* d_in, const int* in_sizes, int n_in,
                              void* d_out, int out_size, void* d_ws, size_t ws_size,
                              hipStream_t stream){
  const float* x      = (const float*)d_in[0];
  const float* fcl1_w = (const float*)d_in[1];  const float* fcl1_b = (const float*)d_in[2];
  const float* fcl2_w = (const float*)d_in[3];  const float* fcl2_b = (const float*)d_in[4];
  const float* fcr1_w = (const float*)d_in[5];  const float* fcr1_b = (const float*)d_in[6];
  const float* fcr2_w = (const float*)d_in[7];  const float* fcr2_b = (const float*)d_in[8];
  const float* fcp1_w = (const float*)d_in[9];  const float* fcp1_b = (const float*)d_in[10];
  const float* fcp2_w = (const float*)d_in[11]; const float* fcp2_b = (const float*)d_in[12];
  const float* Wl0 = (const float*)d_in[13]; const float* bl0 = (const float*)d_in[14];
  const float* Wl1 = (const float*)d_in[15];
  const float* Wr0 = (const float*)d_in[16]; const float* br0 = (const float*)d_in[17];
  const float* Wr1 = (const float*)d_in[18];
  const float* Wp0 = (const float*)d_in[19]; const float* bp0 = (const float*)d_in[20];
  const float* Wp1 = (const float*)d_in[21];
  const float* w_ss = (const float*)d_in[22]; const float* w_sv = (const float*)d_in[23];
  const float* w_vs = (const float*)d_in[24]; const float* w_vv = (const float*)d_in[25];
  float* out = (float*)d_out;

  // ---- ws layout ----
  u16* WT = (u16*)d_ws;
  u16* wt_fcl1 = WT + 0*262144;
  u16* wt_fcl2 = WT + 1*262144;
  u16* wt_fcr1 = WT + 2*262144;
  u16* wt_fcr2 = WT + 3*262144;
  u16* wt_fcp1 = WT + 4*262144;
  u16* wt_fcp2 = WT + 5*262144;
  u16* wt_sm  = WT + 6*262144;
  u16* wt_Wl0 = wt_sm + 0*32768;
  u16* wt_Wl1 = wt_sm + 1*32768;
  u16* wt_Wr0 = wt_sm + 2*32768;
  u16* wt_Wr1 = wt_sm + 3*32768;
  u16* wt_Wp0 = wt_sm + 4*32768;
  u16* wt_Wp1 = wt_sm + 5*32768;
  char* base = (char*)d_ws;
  const size_t SZ512  = (size_t)NP * 512 * 2;
  const size_t SZ1024 = (size_t)NP * 1024 * 2;
  const size_t W_RES  = (size_t)4 << 20;
  u16* A0 = (u16*)(base + W_RES);                       // A0, later A2
  u16* Hl = (u16*)(base + W_RES + 1*SZ512);             // H_l, OL, H_p
  u16* Hr = (u16*)(base + W_RES + 2*SZ512);             // H_r, OR
  u16* BL = (u16*)(base + W_RES + 3*SZ512);             // ls/lv left; later TPV
  u16* BR = (u16*)(base + W_RES + 3*SZ512 + SZ1024);    // ls/lv right; later PS/PV
  (void)ws_size; (void)in_sizes; (void)n_in; (void)out_size;

  // 1. weights -> bf16 transposed
  k_wconv<<<6912, 256, 0, stream>>>(fcl1_w, fcl2_w, fcr1_w, fcr2_w, fcp1_w, fcp2_w,
                                    Wl0, Wl1, Wr0, Wr1, Wp0, Wp1, WT);
  // 2. A0 = [s | ||v||] bf16
  k_prep<<<NP, 256, 0, stream>>>(x, A0);
  // 3. fc1 (L,R)
  k_fc<0,2><<<RT*8, 256, 0, stream>>>(A0, A0, wt_fcl1, wt_fcr1,
                                      fcl1_b, fcr1_b, Hl, Hr, nullptr, nullptr);
  // 4. fc2 (L,R) + gate vs x
  k_fc<1,2><<<RT*8, 256, 0, stream>>>(Hl, Hr, wt_fcl2, wt_fcr2,
                                      fcl2_b, fcr2_b, BL, BR, x, nullptr);
  // 5. o3 linears (2 branches x 4 comps) -> OL(Hl), OR(Hr)
  k_o3<0><<<RT*8, 256, 0, stream>>>(BL, BR, wt_Wl0, wt_Wl1, wt_Wr0, wt_Wr1,
                                    bl0, br0, Hl, Hr, nullptr);
  // 6. tensor product + residual + norms -> A2(A0), TPV(BL)
  k_tp<<<NP/2, 256, 0, stream>>>(Hl, Hr, x, w_ss, w_sv, w_vs, w_vv, A0, BL);
  // 7. fcp1
  k_fc<0,1><<<RT*4, 256, 0, stream>>>(A0, A0, wt_fcp1, wt_fcp1,
                                      fcp1_b, fcp1_b, Hl, Hl, nullptr, nullptr);
  // 8. fcp2 + gate vs TPV
  k_fc<2,1><<<RT*4, 256, 0, stream>>>(Hl, Hl, wt_fcp2, wt_fcp2,
                                      fcp2_b, fcp2_b, BR, BR, nullptr, BL);
  // 9. final o3 -> d_out fp32
  k_o3<1><<<RT*4, 256, 0, stream>>>(BR, BR, wt_Wp0, wt_Wp1, nullptr, nullptr,
                                    bp0, bp0, nullptr, nullptr, out);
}

// Round 3
// 788.154 us; speedup vs baseline: 1.1568x; 1.0920x over previous
//
#include <hip/hip_runtime.h>
#include <cstddef>

#define NN 50000
#define NP 50048      // padded rows (391 * 128)
#define RT 391        // row tiles

typedef unsigned short u16;
typedef __attribute__((ext_vector_type(8))) short bf16x8;
typedef __attribute__((ext_vector_type(4))) float f32x4;

__device__ __forceinline__ float bf2f(u16 h){
  union { unsigned u; float f; } x; x.u = ((unsigned)h) << 16; return x.f;
}
__device__ __forceinline__ u16 f2bf(float f){
  union { float f; unsigned u; } x; x.f = f;
  unsigned r = x.u + 0x7fffu + ((x.u >> 16) & 1u);
  return (u16)(r >> 16);
}
__device__ __forceinline__ float silu_f(float v){
  return v / (1.f + __expf(-v));
}
__device__ __forceinline__ void gll16(const u16* g, u16* l){
  __builtin_amdgcn_global_load_lds(
      (const __attribute__((address_space(1))) unsigned int*)g,
      (__attribute__((address_space(3))) unsigned int*)l, 16, 0, 0);
}
// bijective XCD-chunked block-id swizzle (m204)
__device__ __forceinline__ int xcd_swz(int hw, int nblk){
  int q = nblk >> 3, r = nblk & 7;
  int xcd = hw & 7, j = hw >> 3;
  return (xcd < r ? xcd*(q+1) : r*(q+1) + (xcd - r)*q) + j;
}
#define SWZ(row) (((row) >> 1) & 3)

// ---------------- weight convert + transpose to bf16 (tiled, coalesced) ----
// big (6): [512,512] -> Wt[c][k] at WT + m*262144
// small(6): [256,128] -> Wt[c][k] at WT + 6*262144 + (m-6)*32768
__global__ __launch_bounds__(256)
void k_wt(const float* b0,const float* b1,const float* b2,const float* b3,
          const float* b4,const float* b5,
          const float* s0,const float* s1,const float* s2,const float* s3,
          const float* s4,const float* s5, u16* __restrict__ dst){
  __shared__ float t[64][68];
  const int m = blockIdx.y;
  const bool big = (m < 6);
  const int K = big ? 512 : 256, C = big ? 512 : 128;
  const int tC = C >> 6;
  const int tiles = (K >> 6) * tC;
  if((int)blockIdx.x >= tiles) return;
  const int k0 = ((int)blockIdx.x / tC) << 6, c0 = ((int)blockIdx.x % tC) << 6;
  const float* src = m==0?b0:m==1?b1:m==2?b2:m==3?b3:m==4?b4:m==5?b5:
                     m==6?s0:m==7?s1:m==8?s2:m==9?s3:m==10?s4:s5;
  u16* d = dst + (big ? (size_t)m*262144 : (size_t)(6*262144) + (size_t)(m-6)*32768);
  const int tr = threadIdx.x >> 2, tc = (threadIdx.x & 3) << 4;
  const float* sp = src + (size_t)(k0 + tr)*C + c0 + tc;
#pragma unroll
  for(int j=0;j<16;j+=4) *(f32x4*)&t[tr][tc + j] = *(const f32x4*)(sp + j);
  __syncthreads();
  u16* dp = d + (size_t)(c0 + tr)*K + k0 + tc;
#pragma unroll
  for(int j=0;j<16;j++) dp[j] = f2bf(t[tc + j][tr]);
}

// ---------------- prep: A0 = bf16[ s | ||v|| ]  [NP,512] ----------------
__global__ __launch_bounds__(256)
void k_prep(const float* __restrict__ x, u16* __restrict__ A0){
  const int n = blockIdx.x;
  const int t = threadIdx.x;
  u16* row = A0 + (size_t)n * 512;
  if(n >= NN){ row[t] = 0; row[256 + t] = 0; return; }
  const float* xr = x + (size_t)n * 1024;
  row[t] = f2bf(xr[t]);
  float a = xr[256 + 3*t], b = xr[256 + 3*t + 1], c = xr[256 + 3*t + 2];
  row[256 + t] = f2bf(sqrtf(a*a + b*b + c*c));
}

// ------- 128x128 MFMA tile core: 4-buffer deep pipeline, counted vmcnt ------
// lds: 32768 u16 = 64 KB: 4 bufs x (A 4096 | B 4096)
template<int K>
__device__ __forceinline__ void gemm_core(const u16* __restrict__ A, int lda,
                                          const u16* __restrict__ Bt, int ldb,
                                          u16* lds, f32x4 acc[4][4]){
  const int tid  = threadIdx.x;
  const int lane = tid & 63;
  const int wid  = tid >> 6;
  const int wm = (wid >> 1) << 6;
  const int wn = (wid & 1) << 6;
  const int lr = lane & 15;
  const int lh = lane >> 4;
#pragma unroll
  for(int mi=0;mi<4;mi++)
#pragma unroll
    for(int ni=0;ni<4;ni++) acc[mi][ni] = (f32x4)(0.f);

  // staging: entry e in [0,512): row=e>>2, slot=e&3; global src k-chunk is
  // pre-swizzled (slot ^ SWZ(row)); LDS dest linear (rule #21)
  const int r0 = tid >> 2,        s0 = tid & 3;
  const int r1 = (tid + 256) >> 2;
  const u16* agA0 = A  + (size_t)r0*lda + (size_t)((s0 ^ SWZ(r0)) * 8);
  const u16* agA1 = A  + (size_t)r1*lda + (size_t)((s0 ^ SWZ(r1)) * 8);
  const u16* agB0 = Bt + (size_t)r0*ldb + (size_t)((s0 ^ SWZ(r0)) * 8);
  const u16* agB1 = Bt + (size_t)r1*ldb + (size_t)((s0 ^ SWZ(r1)) * 8);

  constexpr int NT = K / 32;
  static_assert(NT >= 4, "need >=4 K-steps");

#define STAGE(b, k0)                                         \
  { u16* lbase = lds + (size_t)(b) * 8192;                   \
    gll16(agA0 + (k0), lbase + tid*8);                       \
    gll16(agA1 + (k0), lbase + (tid+256)*8);                 \
    gll16(agB0 + (k0), lbase + 4096 + tid*8);                \
    gll16(agB1 + (k0), lbase + 4096 + (tid+256)*8); }

  STAGE(0, 0) STAGE(1, 32) STAGE(2, 64)
  for(int kt = 0; kt < NT; ++kt){
    // 12 outstanding (stages kt..kt+2) -> wait until 8: stage kt landed
    asm volatile("s_waitcnt vmcnt(8)" ::: "memory");
    __builtin_amdgcn_s_barrier();
    const u16* la = lds + (size_t)(kt & 3) * 8192;
    const u16* lb = la + 4096;
    bf16x8 af[4], bv[4];
#pragma unroll
    for(int i=0;i<4;i++){
      const int ra = wm + i*16 + lr;
      af[i] = *(const bf16x8*)(la + ra*32 + ((lh ^ SWZ(ra)) * 8));
      const int rb = wn + i*16 + lr;
      bv[i] = *(const bf16x8*)(lb + rb*32 + ((lh ^ SWZ(rb)) * 8));
    }
    {
      const int nb = (kt + 3) & 3;
      const int kn = ((kt + 3) & (NT - 1)) * 32;   // wrap: uniform vmcnt; tail loads harmless
      STAGE(nb, kn)
    }
#pragma unroll
    for(int mi=0;mi<4;mi++)
#pragma unroll
      for(int ni=0;ni<4;ni++)
        acc[mi][ni] = __builtin_amdgcn_mfma_f32_16x16x32_bf16(
                          af[mi], bv[ni], acc[mi][ni], 0, 0, 0);
  }
#undef STAGE
  // drain wrapped prefetches before LDS reuse by epilogues
  asm volatile("s_waitcnt vmcnt(0)" ::: "memory");
  __builtin_amdgcn_s_barrier();
}

// C-tile LDS staging helpers (bf16, XOR-swizzled: byte ^= (row&7)<<4)
__device__ __forceinline__ void cstage_write(u16* lds, int rl, int cl, float v){
  const int b = ((rl << 8) + (cl << 1)) ^ ((rl & 7) << 4);
  *(u16*)((char*)lds + b) = f2bf(v);
}

// ---------------- fc GEMMs: [NP,512]@[512,512] ----------------
// EPI 0: silu(acc+bias) -> bf16 [n*512+c]
// EPI 1: gate: c<256 silu -> [n*1024+c]; c>=256 raw g, out = x_vec * g
// EPI 2: same but vs TPV
template<int EPI, int NZ>
__global__ __launch_bounds__(256, 2)
void k_fc(const u16* __restrict__ Al, const u16* __restrict__ Ar,
          const u16* __restrict__ Btl, const u16* __restrict__ Btr,
          const float* __restrict__ bl, const float* __restrict__ br_,
          u16* __restrict__ ol, u16* __restrict__ orr,
          const float* __restrict__ xg, const u16* __restrict__ tpv){
  __shared__ u16 lds[32768];
  const int nblk = RT * 4 * NZ;
  const int L = xcd_swz(blockIdx.x, nblk);
  int rowTileI, colTileI, z;
  if(NZ == 2){ rowTileI = L >> 3; int sub = L & 7; colTileI = sub >> 1; z = sub & 1; }
  else       { rowTileI = L >> 2; colTileI = L & 3; z = 0; }
  const u16* A  = z ? Ar  : Al;
  const u16* Bt = z ? Btr : Btl;
  const float* bias = z ? br_ : bl;
  u16* o = z ? orr : ol;
  const int tileRow = rowTileI << 7;
  const int colTile = colTileI << 7;
  f32x4 acc[4][4];
  gemm_core<512>(A + (size_t)tileRow*512, 512, Bt + (size_t)colTile*512, 512,
                 lds, acc);
  const int tid = threadIdx.x, lane = tid & 63, wid = tid >> 6;
  const int wm=(wid>>1)<<6, wn=(wid&1)<<6, lr=lane&15, lh=lane>>4;
  const bool gateTile = (EPI != 0) && (colTile >= 256);
  // stage post-activation values (bf16) into LDS
#pragma unroll
  for(int mi=0;mi<4;mi++){
#pragma unroll
    for(int ni=0;ni<4;ni++){
      const int cl = wn + ni*16 + lr;
      const float bv = bias[colTile + cl];
#pragma unroll
      for(int r=0;r<4;r++){
        const int rl = wm + mi*16 + lh*4 + r;
        float v = acc[mi][ni][r] + bv;
        if(!gateTile) v = silu_f(v);
        cstage_write(lds, rl, cl, v);
      }
    }
  }
  __syncthreads();
  // coalesced write-out: thread -> (row, half), 64 contiguous cols
  const int row = tid >> 1, half = tid & 1;
  const int n = tileRow + row;
  u16 vals[64];
#pragma unroll
  for(int ch=0; ch<8; ++ch){
    const int b = ((row << 8) + ((half*64 + ch*8) << 1)) ^ ((row & 7) << 4);
    *(bf16x8*)(vals + ch*8) = *(const bf16x8*)((const char*)lds + b);
  }
  if(EPI == 0){
    u16* p = o + (size_t)n*512 + colTile + half*64;
#pragma unroll
    for(int ch=0;ch<8;ch++) *(bf16x8*)(p + ch*8) = *(const bf16x8*)(vals + ch*8);
  } else if(!gateTile){
    u16* p = o + (size_t)n*1024 + colTile + half*64;
#pragma unroll
    for(int ch=0;ch<8;ch++) *(bf16x8*)(p + ch*8) = *(const bf16x8*)(vals + ch*8);
  } else {
    const int u0 = (colTile - 256) + half*64;
    u16 o0[64], o1[64], o2[64];
    if(EPI == 1){
      if(n < NN){
        const float* xv = xg + (size_t)n*1024 + 256 + 3*u0;
#pragma unroll
        for(int j=0;j<64;j++){
          float g = bf2f(vals[j]);
          o0[j] = f2bf(xv[3*j]   * g);
          o1[j] = f2bf(xv[3*j+1] * g);
          o2[j] = f2bf(xv[3*j+2] * g);
        }
      } else {
#pragma unroll
        for(int j=0;j<64;j++){ o0[j]=0; o1[j]=0; o2[j]=0; }
      }
    } else {
      const u16* tv = tpv + (size_t)n*768 + u0;
#pragma unroll
      for(int j=0;j<64;j++){
        float g = bf2f(vals[j]);
        o0[j] = f2bf(bf2f(tv[j])     * g);
        o1[j] = f2bf(bf2f(tv[256+j]) * g);
        o2[j] = f2bf(bf2f(tv[512+j]) * g);
      }
    }
    u16* p = o + (size_t)n*1024 + 256 + u0;
#pragma unroll
    for(int ch=0;ch<8;ch++){
      *(bf16x8*)(p + ch*8)       = *(const bf16x8*)(o0 + ch*8);
      *(bf16x8*)(p + 256 + ch*8) = *(const bf16x8*)(o1 + ch*8);
      *(bf16x8*)(p + 512 + ch*8) = *(const bf16x8*)(o2 + ch*8);
    }
  }
}

// ---------------- o3 GEMMs: [NP,256]@[256,128] ----------------
template<int EPI>
__global__ __launch_bounds__(256, 2)
void k_o3(const u16* __restrict__ AL, const u16* __restrict__ AR,
          const u16* __restrict__ W0L, const u16* __restrict__ W1L,
          const u16* __restrict__ W0R, const u16* __restrict__ W1R,
          const float* __restrict__ bL, const float* __restrict__ bR,
          u16* __restrict__ oL, u16* __restrict__ oR,
          float* __restrict__ fout){
  __shared__ u16 lds[32768];
  const int nblk = RT * ((EPI==0) ? 8 : 4);
  const int L = xcd_swz(blockIdx.x, nblk);
  int rowTileI, br, comp;
  if(EPI == 0){ rowTileI = L >> 3; int sub = L & 7; br = sub >> 2; comp = sub & 3; }
  else        { rowTileI = L >> 2; comp = L & 3; br = 0; }
  const u16* A  = br ? AR : AL;
  const u16* Bt = br ? (comp ? W1R : W0R) : (comp ? W1L : W0L);
  const float* bias = br ? bR : bL;
  u16* o16 = br ? oR : oL;
  const int aoff = comp ? (256 + (comp-1)*256) : 0;
  const int tileRow = rowTileI << 7;
  f32x4 acc[4][4];
  gemm_core<256>(A + (size_t)tileRow*1024 + aoff, 1024, Bt, 256, lds, acc);
  const int tid = threadIdx.x, lane = tid & 63, wid = tid >> 6;
  const int wm=(wid>>1)<<6, wn=(wid&1)<<6, lr=lane&15, lh=lane>>4;
  if(EPI == 0){
#pragma unroll
    for(int mi=0;mi<4;mi++){
#pragma unroll
      for(int ni=0;ni<4;ni++){
        const int cl = wn + ni*16 + lr;
#pragma unroll
        for(int r=0;r<4;r++){
          const int rl = wm + mi*16 + lh*4 + r;
          float v = acc[mi][ni][r] * 0.0625f;
          if(comp == 0) v += bias[cl];
          cstage_write(lds, rl, cl, v);
        }
      }
    }
    __syncthreads();
    const int row = tid >> 1, half = tid & 1;
    const int n = tileRow + row;
    u16 vals[64];
#pragma unroll
    for(int ch=0; ch<8; ++ch){
      const int b = ((row << 8) + ((half*64 + ch*8) << 1)) ^ ((row & 7) << 4);
      *(bf16x8*)(vals + ch*8) = *(const bf16x8*)((const char*)lds + b);
    }
    u16* p = o16 + (size_t)n*512 + comp*128 + half*64;
#pragma unroll
    for(int ch=0;ch<8;ch++) *(bf16x8*)(p + ch*8) = *(const bf16x8*)(vals + ch*8);
  } else {
#pragma unroll
    for(int mi=0;mi<4;mi++){
#pragma unroll
      for(int ni=0;ni<4;ni++){
        const int c = wn + ni*16 + lr;
#pragma unroll
        for(int r=0;r<4;r++){
          const int n = tileRow + wm + mi*16 + lh*4 + r;
          float v = acc[mi][ni][r] * 0.0625f;
          if(n < NN){
            if(comp == 0) fout[(size_t)n*512 + c] = v + bias[c];
            else          fout[(size_t)n*512 + 128 + c*3 + (comp-1)] = v;
          }
        }
      }
    }
  }
}

// ------------- TP + residual + norms: builds A2 [NP,512], TPV [NP,3,256] ---
__global__ __launch_bounds__(256)
void k_tp(const u16* __restrict__ OL, const u16* __restrict__ ORr,
          const float* __restrict__ x,
          const float* __restrict__ w_ss, const float* __restrict__ w_sv,
          const float* __restrict__ w_vs, const float* __restrict__ w_vv,
          u16* __restrict__ A2, u16* __restrict__ TPV){
  const int n = (blockIdx.x << 1) + (threadIdx.x >> 7);
  const int h = threadIdx.x & 127;
  const u16* ol  = OL  + (size_t)n * 512;
  const u16* orv = ORr + (size_t)n * 512;
  const float ls = bf2f(ol[h]),  rs = bf2f(orv[h]);
  const float lv0=bf2f(ol[128+h]),  lv1=bf2f(ol[256+h]),  lv2=bf2f(ol[384+h]);
  const float rv0=bf2f(orv[128+h]), rv1=bf2f(orv[256+h]), rv2=bf2f(orv[384+h]);
  const float wss=w_ss[h], wsv=w_sv[h], wvs=w_vs[h], wvv=w_vv[h];
  float sa = wss * ls * rs;
  float sb = wvv * (lv0*rv0 + lv1*rv1 + lv2*rv2) * 0.5773502691896258f;
  float va0 = wsv*ls*rv0, va1 = wsv*ls*rv1, va2 = wsv*ls*rv2;
  float vb0 = wvs*lv0*rs, vb1 = wvs*lv1*rs, vb2 = wvs*lv2*rs;
  if(n < NN){
    const float* xr = x + (size_t)n * 1024;
    sa += xr[h]; sb += xr[128 + h];
    va0 += xr[256 + 3*h];     va1 += xr[256 + 3*h + 1];   va2 += xr[256 + 3*h + 2];
    const int h2 = 128 + h;
    vb0 += xr[256 + 3*h2];    vb1 += xr[256 + 3*h2 + 1];  vb2 += xr[256 + 3*h2 + 2];
  }
  u16* a2 = A2 + (size_t)n * 512;
  a2[h]       = f2bf(sa);
  a2[128 + h] = f2bf(sb);
  a2[256 + h] = f2bf(sqrtf(va0*va0 + va1*va1 + va2*va2));
  a2[384 + h] = f2bf(sqrtf(vb0*vb0 + vb1*vb1 + vb2*vb2));
  u16* tv = TPV + (size_t)n * 768;
  tv[h]       = f2bf(va0);  tv[128 + h] = f2bf(vb0);
  tv[256 + h] = f2bf(va1);  tv[384 + h] = f2bf(vb1);
  tv[512 + h] = f2bf(va2);  tv[640 + h] = f2bf(vb2);
}

extern "C" void kernel_launch(void* const* d_in, const int* in_sizes, int n_in,
                              void* d_out, int out_size, void* d_ws, size_t ws_size,
                              hipStream_t stream){
  const float* x      = (const float*)d_in[0];
  const float* fcl1_w = (const float*)d_in[1];  const float* fcl1_b = (const float*)d_in[2];
  const float* fcl2_w = (const float*)d_in[3];  const float* fcl2_b = (const float*)d_in[4];
  const float* fcr1_w = (const float*)d_in[5];  const float* fcr1_b = (const float*)d_in[6];
  const float* fcr2_w = (const float*)d_in[7];  const float* fcr2_b = (const float*)d_in[8];
  const float* fcp1_w = (const float*)d_in[9];  const float* fcp1_b = (const float*)d_in[10];
  const float* fcp2_w = (const float*)d_in[11]; const float* fcp2_b = (const float*)d_in[12];
  const float* Wl0 = (const float*)d_in[13]; const float* bl0 = (const float*)d_in[14];
  const float* Wl1 = (const float*)d_in[15];
  const float* Wr0 = (const float*)d_in[16]; const float* br0 = (const float*)d_in[17];
  const float* Wr1 = (const float*)d_in[18];
  const float* Wp0 = (const float*)d_in[19]; const float* bp0 = (const float*)d_in[20];
  const float* Wp1 = (const float*)d_in[21];
  const float* w_ss = (const float*)d_in[22]; const float* w_sv = (const float*)d_in[23];
  const float* w_vs = (const float*)d_in[24]; const float* w_vv = (const float*)d_in[25];
  float* out = (float*)d_out;

  // ---- ws layout ----
  u16* WT = (u16*)d_ws;
  u16* wt_fcl1 = WT + 0*262144;
  u16* wt_fcl2 = WT + 1*262144;
  u16* wt_fcr1 = WT + 2*262144;
  u16* wt_fcr2 = WT + 3*262144;
  u16* wt_fcp1 = WT + 4*262144;
  u16* wt_fcp2 = WT + 5*262144;
  u16* wt_sm  = WT + 6*262144;
  u16* wt_Wl0 = wt_sm + 0*32768;
  u16* wt_Wl1 = wt_sm + 1*32768;
  u16* wt_Wr0 = wt_sm + 2*32768;
  u16* wt_Wr1 = wt_sm + 3*32768;
  u16* wt_Wp0 = wt_sm + 4*32768;
  u16* wt_Wp1 = wt_sm + 5*32768;
  char* base = (char*)d_ws;
  const size_t SZ512  = (size_t)NP * 512 * 2;
  const size_t SZ1024 = (size_t)NP * 1024 * 2;
  const size_t W_RES  = (size_t)4 << 20;
  u16* A0 = (u16*)(base + W_RES);                       // A0, later A2
  u16* Hl = (u16*)(base + W_RES + 1*SZ512);             // H_l, OL, H_p
  u16* Hr = (u16*)(base + W_RES + 2*SZ512);             // H_r, OR
  u16* BL = (u16*)(base + W_RES + 3*SZ512);             // ls/lv left; later TPV
  u16* BR = (u16*)(base + W_RES + 3*SZ512 + SZ1024);    // ls/lv right; later PS/PV
  (void)ws_size; (void)in_sizes; (void)n_in; (void)out_size;

  // 1. weights -> bf16 transposed (tiled)
  k_wt<<<dim3(64,12), 256, 0, stream>>>(fcl1_w, fcl2_w, fcr1_w, fcr2_w, fcp1_w, fcp2_w,
                                        Wl0, Wl1, Wr0, Wr1, Wp0, Wp1, WT);
  // 2. A0 = [s | ||v||] bf16
  k_prep<<<NP, 256, 0, stream>>>(x, A0);
  // 3. fc1 (L,R)
  k_fc<0,2><<<RT*8, 256, 0, stream>>>(A0, A0, wt_fcl1, wt_fcr1,
                                      fcl1_b, fcr1_b, Hl, Hr, nullptr, nullptr);
  // 4. fc2 (L,R) + gate vs x
  k_fc<1,2><<<RT*8, 256, 0, stream>>>(Hl, Hr, wt_fcl2, wt_fcr2,
                                      fcl2_b, fcr2_b, BL, BR, x, nullptr);
  // 5. o3 linears (2 branches x 4 comps) -> OL(Hl), OR(Hr)
  k_o3<0><<<RT*8, 256, 0, stream>>>(BL, BR, wt_Wl0, wt_Wl1, wt_Wr0, wt_Wr1,
                                    bl0, br0, Hl, Hr, nullptr);
  // 6. tensor product + residual + norms -> A2(A0), TPV(BL)
  k_tp<<<NP/2, 256, 0, stream>>>(Hl, Hr, x, w_ss, w_sv, w_vs, w_vv, A0, BL);
  // 7. fcp1
  k_fc<0,1><<<RT*4, 256, 0, stream>>>(A0, A0, wt_fcp1, wt_fcp1,
                                      fcp1_b, fcp1_b, Hl, Hl, nullptr, nullptr);
  // 8. fcp2 + gate vs TPV
  k_fc<2,1><<<RT*4, 256, 0, stream>>>(Hl, Hl, wt_fcp2, wt_fcp2,
                                      fcp2_b, fcp2_b, BR, BR, nullptr, BL);
  // 9. final o3 -> d_out fp32
  k_o3<1><<<RT*4, 256, 0, stream>>>(BR, BR, wt_Wp0, wt_Wp1, nullptr, nullptr,
                                    bp0, bp0, nullptr, nullptr, out);
}